// Round 3
// baseline (848.362 us; speedup 1.0000x reference)
//
#include <hip/hip_runtime.h>

#define GRID   512
#define BLOCK  512
#define BATCH  16384
#define NJ     25
#define DEPTH  256
#define ITERS  (BATCH / GRID)   // 32

typedef short s16x8 __attribute__((ext_vector_type(8)));
typedef short s16x4 __attribute__((ext_vector_type(4)));
typedef float f32x4 __attribute__((ext_vector_type(4)));

// fp32 -> bf16 round-to-nearest-even
__device__ __forceinline__ short f2bf(float f) {
  union { float f; unsigned u; } c; c.f = f;
  unsigned r = (c.u + 0x7FFFu + ((c.u >> 16) & 1u)) >> 16;
  return (short)r;
}

#define MFMA(a, b, c) __builtin_amdgcn_mfma_f32_16x16x32_bf16((a), (b), (c), 0, 0, 0)

// 8 waves x 32 output cols (wf[8][2] = 64 VGPR -> 4 waves/SIMD) with round-2's
// barrier discipline: single As buffer, prefetch held in registers across barA,
// 2 barriers/iter, stores issued last and drained (aged) at next iter's barA.
// As XOR-swizzled in 16B chunks (conflict-free ds_read_b128); Yt pitch-32 swizzled.
__global__ __launch_bounds__(BLOCK, 4)
void geo_gcn_fused(const float* __restrict__ x,
                   const float* __restrict__ w,
                   float* __restrict__ out)
{
  __shared__ short As[32][256];     // 16384 B, swizzled, single buffer
  __shared__ short Ps[32][40];      //  2560 B
  __shared__ float S3[32][33];      //  4224 B
  __shared__ short Yt[8][32][32];   // 16384 B, swizzled  -> 39552 B total

  const int tid  = threadIdx.x;
  const int wv   = tid >> 6;        // 0..7, owns cols [32*wv, 32*wv+32)
  const int lane = tid & 63;
  const int quad = lane >> 4;
  const int l16  = lane & 15;

  // ---- persistent W fragments: wf[ks][td][j] = W[ks*32+quad*8+j][wv*32+td*16+l16]
  s16x8 wf[8][2];
  {
    const int ncol = wv * 32 + l16;
#pragma unroll
    for (int ks = 0; ks < 8; ++ks)
#pragma unroll
      for (int td = 0; td < 2; ++td) {
        const float* wp = w + (size_t)(ks * 32 + quad * 8) * DEPTH + ncol + td * 16;
#pragma unroll
        for (int j = 0; j < 8; ++j)
          wf[ks][td][j] = f2bf(wp[(size_t)j * DEPTH]);
      }
  }

  const int tm_s = (wv >> 1) & 1;   // s3 tile (tm_s, tn_s), waves 0..3
  const int tn_s = wv & 1;
  const int srow = tid >> 4;        // staging row 0..31 (rows >= NJ stay zero)
  const int sc   = tid & 15;        // 16 threads/row, 16 floats each
  // swizzle: phys_chunk(16B) = logical_chunk ^ (row & 7); thread owns chunks 2sc,2sc+1
  const int sw0  = ((2 * sc)     ^ (srow & 7)) * 8;   // shorts
  const int sw1  = ((2 * sc + 1) ^ (srow & 7)) * 8;

  const float* xb = x + (size_t)srow * BATCH * DEPTH + sc * 16;

  // ---- prologue: stage element blockIdx.x ----
  {
    float4 c0 = make_float4(0.f,0.f,0.f,0.f), c1 = c0, c2 = c0, c3 = c0;
    if (srow < NJ) {
      const float* xp = xb + (size_t)blockIdx.x * DEPTH;
      c0 = *(const float4*)(xp + 0);  c1 = *(const float4*)(xp + 4);
      c2 = *(const float4*)(xp + 8);  c3 = *(const float4*)(xp + 12);
    }
    s16x8 h0, h1;
    h0[0]=f2bf(c0.x); h0[1]=f2bf(c0.y); h0[2]=f2bf(c0.z); h0[3]=f2bf(c0.w);
    h0[4]=f2bf(c1.x); h0[5]=f2bf(c1.y); h0[6]=f2bf(c1.z); h0[7]=f2bf(c1.w);
    h1[0]=f2bf(c2.x); h1[1]=f2bf(c2.y); h1[2]=f2bf(c2.z); h1[3]=f2bf(c2.w);
    h1[4]=f2bf(c3.x); h1[5]=f2bf(c3.y); h1[6]=f2bf(c3.z); h1[7]=f2bf(c3.w);
    *(s16x8*)&As[srow][sw0] = h0;
    *(s16x8*)&As[srow][sw1] = h1;
  }
  __syncthreads();

  for (int ib = 0; ib < ITERS; ++ib) {
    const int b = blockIdx.x + GRID * ib;

    // ---- issue NEXT element's loads now; consumed after barA (aged by K-loop) ----
    float4 nf0 = make_float4(0.f,0.f,0.f,0.f), nf1 = nf0, nf2 = nf0, nf3 = nf0;
    if ((ib + 1 < ITERS) && (srow < NJ)) {
      const float* xp = xb + (size_t)(b + GRID) * DEPTH;
      nf0 = *(const float4*)(xp + 0);  nf1 = *(const float4*)(xp + 4);
      nf2 = *(const float4*)(xp + 8);  nf3 = *(const float4*)(xp + 12);
    }

    f32x4 sacc = (f32x4){0.f, 0.f, 0.f, 0.f};
    f32x4 yacc[2][2];
#pragma unroll
    for (int i = 0; i < 2; ++i)
#pragma unroll
      for (int j = 0; j < 2; ++j) yacc[i][j] = (f32x4){0.f, 0.f, 0.f, 0.f};

    // ---- K loop: 8 x K=32, barrier-free, swizzled conflict-free reads ----
#pragma unroll
    for (int ks = 0; ks < 8; ++ks) {
      const int co = (((ks * 4 + quad) ^ (l16 & 7)) << 3);
      s16x8 a0 = *(const s16x8*)&As[l16][co];
      s16x8 a1 = *(const s16x8*)&As[16 + l16][co];
      if (wv < 4) sacc = MFMA(tm_s ? a1 : a0, tn_s ? a1 : a0, sacc);
      yacc[0][0] = MFMA(a0, wf[ks][0], yacc[0][0]);
      yacc[0][1] = MFMA(a0, wf[ks][1], yacc[0][1]);
      yacc[1][0] = MFMA(a1, wf[ks][0], yacc[1][0]);
      yacc[1][1] = MFMA(a1, wf[ks][1], yacc[1][1]);
    }

    // ---- s3 -> LDS (waves 0..3 own the 4 16x16 tiles) ----
    if (wv < 4) {
#pragma unroll
      for (int r = 0; r < 4; ++r)
        S3[tm_s * 16 + quad * 4 + r][tn_s * 16 + l16] = sacc[r];
    }
    __syncthreads();   // barA: all As reads done; aged prefetch + prev stores drain

    // ---- stage NEXT element into As (same buffer, reads all done at barA) ----
    if (ib + 1 < ITERS) {
      s16x8 h0, h1;
      h0[0]=f2bf(nf0.x); h0[1]=f2bf(nf0.y); h0[2]=f2bf(nf0.z); h0[3]=f2bf(nf0.w);
      h0[4]=f2bf(nf1.x); h0[5]=f2bf(nf1.y); h0[6]=f2bf(nf1.z); h0[7]=f2bf(nf1.w);
      h1[0]=f2bf(nf2.x); h1[1]=f2bf(nf2.y); h1[2]=f2bf(nf2.z); h1[3]=f2bf(nf2.w);
      h1[4]=f2bf(nf3.x); h1[5]=f2bf(nf3.y); h1[6]=f2bf(nf3.z); h1[7]=f2bf(nf3.w);
      *(s16x8*)&As[srow][sw0] = h0;
      *(s16x8*)&As[srow][sw1] = h1;
    }

    // ---- wave-parallel softmax: 8 lanes/row over 32 rows (waves 0..3) ----
    if (tid < 256) {
      const int row = tid >> 3, c8 = tid & 7;
      float v[4]; float mx = -3.0e38f;
#pragma unroll
      for (int i = 0; i < 4; ++i) {
        const int j = c8 + 8 * i;
        v[i] = (j < NJ) ? S3[row][j] : -3.0e38f;
        mx = fmaxf(mx, v[i]);
      }
      mx = fmaxf(mx, __shfl_xor(mx, 1));
      mx = fmaxf(mx, __shfl_xor(mx, 2));
      mx = fmaxf(mx, __shfl_xor(mx, 4));
      float e[4]; float sum = 0.f;
#pragma unroll
      for (int i = 0; i < 4; ++i) {
        const int j = c8 + 8 * i;
        e[i] = (j < NJ) ? __expf(v[i] - mx) : 0.f;
        sum += e[i];
      }
      sum += __shfl_xor(sum, 1);
      sum += __shfl_xor(sum, 2);
      sum += __shfl_xor(sum, 4);
      const float rinv = 1.0f / sum;
#pragma unroll
      for (int i = 0; i < 4; ++i)
        Ps[row][c8 + 8 * i] = f2bf(e[i] * rinv);   // cols >= NJ get exact 0
    }
    __syncthreads();   // barB: LDS-only drain (cheap)

    // ---- Y (C-layout) -> Yt, swizzled: phys_chunk = logical_chunk ^ (d & 3) ----
#pragma unroll
    for (int tm = 0; tm < 2; ++tm)
#pragma unroll
      for (int td = 0; td < 2; ++td) {
        s16x4 hy;
#pragma unroll
        for (int r = 0; r < 4; ++r) hy[r] = f2bf(yacc[tm][td][r]);
        // d = td*16+l16 (d&3 == l16&3); m-chunk = tm*2 + (quad>>1)
        const int pc = ((tm * 2 + (quad >> 1)) ^ (l16 & 3)) * 8 + (quad & 1) * 4;
        *(s16x4*)&Yt[wv][td * 16 + l16][pc] = hy;
      }
    // same-wave DS ordering: Yt writes precede this wave's Yt reads in issue order

    // ---- out_strip = P @ Y_strip; stores issued LAST, no trailing barrier ----
    s16x8 pf0 = *(const s16x8*)&Ps[l16][quad * 8];
    s16x8 pf1 = *(const s16x8*)&Ps[16 + l16][quad * 8];
    const f32x4 z4 = (f32x4){0.f, 0.f, 0.f, 0.f};
    float* ob = out + (size_t)b * NJ * DEPTH + wv * 32 + l16;
#pragma unroll
    for (int td = 0; td < 2; ++td) {
      const int rc = (quad ^ (l16 & 3)) * 8;   // m-chunk quad, swizzled
      s16x8 yb = *(const s16x8*)&Yt[wv][td * 16 + l16][rc];
      f32x4 o0 = MFMA(pf0, yb, z4);
      f32x4 o1 = MFMA(pf1, yb, z4);
#pragma unroll
      for (int r = 0; r < 4; ++r) {
        ob[(size_t)(quad * 4 + r) * DEPTH + td * 16] = o0[r];   // rows 0..15
        const int nr = 16 + quad * 4 + r;                       // rows 16..24
        if (nr < NJ) ob[(size_t)nr * DEPTH + td * 16] = o1[r];
      }
    }
    // next iter's As reads gated by barB; stores drain at next iter's barA.
  }
}

extern "C" void kernel_launch(void* const* d_in, const int* in_sizes, int n_in,
                              void* d_out, int out_size, void* d_ws, size_t ws_size,
                              hipStream_t stream) {
  (void)in_sizes; (void)n_in; (void)out_size; (void)d_ws; (void)ws_size;
  const float* x = (const float*)d_in[0];
  const float* w = (const float*)d_in[1];
  float* out = (float*)d_out;
  geo_gcn_fused<<<dim3(GRID), dim3(BLOCK), 0, stream>>>(x, w, out);
}

// Round 4
// 712.124 us; speedup vs baseline: 1.1913x; 1.1913x over previous
//
#include <hip/hip_runtime.h>

#define GRID   1024
#define BLOCK  256
#define BATCH  16384
#define NJ     25
#define DEPTH  256
#define ITERS  (BATCH / GRID)   // 16

typedef short s16x8 __attribute__((ext_vector_type(8)));
typedef short s16x4 __attribute__((ext_vector_type(4)));
typedef float f32x4 __attribute__((ext_vector_type(4)));

// fp32 -> bf16 round-to-nearest-even
__device__ __forceinline__ short f2bf(float f) {
  union { float f; unsigned u; } c; c.f = f;
  unsigned r = (c.u + 0x7FFFu + ((c.u >> 16) & 1u)) >> 16;
  return (short)r;
}

#define MFMA(a, b, c) __builtin_amdgcn_mfma_f32_16x16x32_bf16((a), (b), (c), 0, 0, 0)

// Round-2 structure (proven ~180us steady): 4 waves x 64 cols, wf[8][4],
// 2 barriers/iter, stores issued last (drain aged at next barA).
// Round-4 fixes: (1) Yt [64][32] XOR-swizzled phys_chunk = c ^ ((d>>1)&3)
// -> conflict-free b128 reads (8-lane phase banks all distinct);
// (2) S3 pitch 36 (2-way max on writes); (3) single As buffer (LDS 39.7KB).
__global__ __launch_bounds__(BLOCK, 2)
void geo_gcn_fused(const float* __restrict__ x,
                   const float* __restrict__ w,
                   float* __restrict__ out)
{
  __shared__ short As[32][256];     // 16384 B, chunk-swizzled, single buffer
  __shared__ short Ps[32][40];      //  2560 B (b128 reads: (5l+q)%8 distinct, clean)
  __shared__ float S3[32][36];      //  4608 B
  __shared__ short Yt[4][64][32];   // 16384 B, swizzled  -> 39936 B total

  const int tid  = threadIdx.x;
  const int wv   = tid >> 6;        // 0..3, owns cols [64*wv, 64*wv+64)
  const int lane = tid & 63;
  const int quad = lane >> 4;
  const int l16  = lane & 15;

  // ---- persistent W fragments: wf[ks][td][j] = W[ks*32+quad*8+j][wv*64+td*16+l16]
  s16x8 wf[8][4];
  {
    const int ncol = wv * 64 + l16;
#pragma unroll
    for (int ks = 0; ks < 8; ++ks)
#pragma unroll
      for (int td = 0; td < 4; ++td) {
        const float* wp = w + (size_t)(ks * 32 + quad * 8) * DEPTH + ncol + td * 16;
#pragma unroll
        for (int j = 0; j < 8; ++j)
          wf[ks][td][j] = f2bf(wp[(size_t)j * DEPTH]);
      }
  }

  const int tm_s = wv >> 1;         // s3 tile (tm_s, tn_s) per wave
  const int tn_s = wv & 1;
  const int srow = tid >> 3;        // staging row 0..31 (rows >= NJ stay zero)
  const int sq   = tid & 7;         // 8 threads/row, 32 floats each
  const int ssw  = (sq ^ (srow & 7)) * 8;   // swizzled chunk offset (shorts)

  const float* xb = x + (size_t)srow * BATCH * DEPTH + sq * 8;

  // ---- prologue: stage element blockIdx.x into As ----
  {
    const float* xp = xb + (size_t)blockIdx.x * DEPTH;
#pragma unroll
    for (int c = 0; c < 4; ++c) {
      float4 c0 = make_float4(0.f, 0.f, 0.f, 0.f), c1 = c0;
      if (srow < NJ) {
        c0 = *(const float4*)(xp + c * 64);
        c1 = *(const float4*)(xp + c * 64 + 4);
      }
      s16x8 h;
      h[0]=f2bf(c0.x); h[1]=f2bf(c0.y); h[2]=f2bf(c0.z); h[3]=f2bf(c0.w);
      h[4]=f2bf(c1.x); h[5]=f2bf(c1.y); h[6]=f2bf(c1.z); h[7]=f2bf(c1.w);
      *(s16x8*)&As[srow][ssw + c * 64] = h;
    }
  }
  __syncthreads();

  for (int ib = 0; ib < ITERS; ++ib) {
    const int b = blockIdx.x + GRID * ib;

    // ---- issue NEXT element's loads; consumed after barA (aged ~0.5 iter) ----
    float4 nf[8];
#pragma unroll
    for (int i = 0; i < 8; ++i) nf[i] = make_float4(0.f, 0.f, 0.f, 0.f);
    if ((ib + 1 < ITERS) && (srow < NJ)) {
      const float* xp = xb + (size_t)(b + GRID) * DEPTH;
#pragma unroll
      for (int c = 0; c < 4; ++c) {
        nf[2 * c]     = *(const float4*)(xp + c * 64);
        nf[2 * c + 1] = *(const float4*)(xp + c * 64 + 4);
      }
    }

    f32x4 sacc = (f32x4){0.f, 0.f, 0.f, 0.f};
    f32x4 yacc[2][4];
#pragma unroll
    for (int i = 0; i < 2; ++i)
#pragma unroll
      for (int j = 0; j < 4; ++j) yacc[i][j] = (f32x4){0.f, 0.f, 0.f, 0.f};

    // ---- K loop: 8 x K=32, barrier-free, swizzled reads (2-way max, free) ----
#pragma unroll
    for (int ks = 0; ks < 8; ++ks) {
      const int co = (((ks * 4 + quad) ^ (l16 & 7)) << 3);
      s16x8 a0 = *(const s16x8*)&As[l16][co];
      s16x8 a1 = *(const s16x8*)&As[16 + l16][co];
      sacc = MFMA(tm_s ? a1 : a0, tn_s ? a1 : a0, sacc);
#pragma unroll
      for (int td = 0; td < 4; ++td) {
        yacc[0][td] = MFMA(a0, wf[ks][td], yacc[0][td]);
        yacc[1][td] = MFMA(a1, wf[ks][td], yacc[1][td]);
      }
    }

    // ---- s3 -> LDS (pitch 36: bank = 16q+4r+l, 2-way max) ----
#pragma unroll
    for (int r = 0; r < 4; ++r)
      S3[tm_s * 16 + quad * 4 + r][tn_s * 16 + l16] = sacc[r];
    __syncthreads();   // barA: all As reads done; prefetch + prev stores aged

    // ---- stage NEXT element into As (reads complete at barA) ----
    if (ib + 1 < ITERS) {
#pragma unroll
      for (int c = 0; c < 4; ++c) {
        s16x8 h;
        h[0]=f2bf(nf[2*c].x);   h[1]=f2bf(nf[2*c].y);
        h[2]=f2bf(nf[2*c].z);   h[3]=f2bf(nf[2*c].w);
        h[4]=f2bf(nf[2*c+1].x); h[5]=f2bf(nf[2*c+1].y);
        h[6]=f2bf(nf[2*c+1].z); h[7]=f2bf(nf[2*c+1].w);
        *(s16x8*)&As[srow][ssw + c * 64] = h;
      }
    }

    // ---- wave-parallel softmax: 8 lanes/row over 32 rows ----
    {
      const int row = tid >> 3, c8 = tid & 7;
      float v[4]; float mx = -3.0e38f;
#pragma unroll
      for (int i = 0; i < 4; ++i) {
        const int j = c8 + 8 * i;
        v[i] = (j < NJ) ? S3[row][j] : -3.0e38f;
        mx = fmaxf(mx, v[i]);
      }
      mx = fmaxf(mx, __shfl_xor(mx, 1));
      mx = fmaxf(mx, __shfl_xor(mx, 2));
      mx = fmaxf(mx, __shfl_xor(mx, 4));
      float e[4]; float sum = 0.f;
#pragma unroll
      for (int i = 0; i < 4; ++i) {
        const int j = c8 + 8 * i;
        e[i] = (j < NJ) ? __expf(v[i] - mx) : 0.f;
        sum += e[i];
      }
      sum += __shfl_xor(sum, 1);
      sum += __shfl_xor(sum, 2);
      sum += __shfl_xor(sum, 4);
      const float rinv = 1.0f / sum;
#pragma unroll
      for (int i = 0; i < 4; ++i)
        Ps[row][c8 + 8 * i] = f2bf(e[i] * rinv);   // cols >= NJ get exact 0
    }
    __syncthreads();   // barB: LDS-only drain (cheap)

    // ---- Y (C-layout) -> Yt, phys_chunk = logical ^ ((d>>1)&3) ----
#pragma unroll
    for (int tm = 0; tm < 2; ++tm)
#pragma unroll
      for (int td = 0; td < 4; ++td) {
        s16x4 hy;
#pragma unroll
        for (int r = 0; r < 4; ++r) hy[r] = f2bf(yacc[tm][td][r]);
        const int pc = (tm * 2 + (quad >> 1)) ^ ((l16 >> 1) & 3);
        *(s16x4*)&Yt[wv][td * 16 + l16][pc * 8 + (quad & 1) * 4] = hy;
      }
    // same-wave DS ordering: Yt writes precede this wave's Yt reads

    // ---- out_strip = P @ Y_strip; stores issued LAST, no trailing barrier ----
    s16x8 pf0 = *(const s16x8*)&Ps[l16][quad * 8];
    s16x8 pf1 = *(const s16x8*)&Ps[16 + l16][quad * 8];
    const f32x4 z4 = (f32x4){0.f, 0.f, 0.f, 0.f};
    float* ob = out + (size_t)b * NJ * DEPTH + wv * 64 + l16;
#pragma unroll
    for (int td = 0; td < 4; ++td) {
      const int pr = quad ^ ((l16 >> 1) & 3);    // conflict-free swizzled read
      s16x8 yb = *(const s16x8*)&Yt[wv][td * 16 + l16][pr * 8];
      f32x4 o0 = MFMA(pf0, yb, z4);
      f32x4 o1 = MFMA(pf1, yb, z4);
#pragma unroll
      for (int r = 0; r < 4; ++r) {
        ob[(size_t)(quad * 4 + r) * DEPTH + td * 16] = o0[r];   // rows 0..15
        const int nr = 16 + quad * 4 + r;                       // rows 16..24
        if (nr < NJ) ob[(size_t)nr * DEPTH + td * 16] = o1[r];
      }
    }
    // next iter's As reads gated by barB; stores drain at next iter's barA.
  }
}

extern "C" void kernel_launch(void* const* d_in, const int* in_sizes, int n_in,
                              void* d_out, int out_size, void* d_ws, size_t ws_size,
                              hipStream_t stream) {
  (void)in_sizes; (void)n_in; (void)out_size; (void)d_ws; (void)ws_size;
  const float* x = (const float*)d_in[0];
  const float* w = (const float*)d_in[1];
  float* out = (float*)d_out;
  geo_gcn_fused<<<dim3(GRID), dim3(BLOCK), 0, stream>>>(x, w, out);
}